// Round 16
// baseline (126.997 us; speedup 1.0000x reference)
//
#include <hip/hip_runtime.h>

#define NBINS   1024
#define CAPC    4096
#define TARGETC 192
#define CAPW    256    // hard cap on compacted candidates (4 slots x 64 lanes)
#define NSLOT   4
#define DET     100
#define XCLIP   4.135166556742356f
#define CHUNK   24
#define TILE4   576    // 546 used float4 slots + clamp pad
#define K2GRID  64     // 1 block/CU -> guaranteed co-resident

__device__ inline float scalar_to_float(const int* p) {
  int v = *p;
  return (v >= 0 && v < (1 << 20)) ? (float)v : __int_as_float(v);
}

struct Box { float x1, y1, x2, y2; };

__device__ inline Box decode_clip(float4 r, float4 p, float W, float H) {
  float w = p.z - p.x, h = p.w - p.y;
  float cx = p.x + 0.5f * w, cy = p.y + 0.5f * h;
  float dx = r.x / 10.f, dy = r.y / 10.f;
  float dw = fminf(r.z / 5.f, XCLIP), dh = fminf(r.w / 5.f, XCLIP);
  float pcx = dx * w + cx, pcy = dy * h + cy;
  float pw = __expf(dw) * w, ph = __expf(dh) * h;
  Box b;
  b.x1 = fminf(fmaxf(pcx - 0.5f * pw, 0.f), W);
  b.y1 = fminf(fmaxf(pcy - 0.5f * ph, 0.f), H);
  b.x2 = fminf(fmaxf(pcx + 0.5f * pw, 0.f), W);
  b.y2 = fminf(fmaxf(pcy + 0.5f * ph, 0.f), H);
  return b;
}

// K1 (R15, unchanged): global_load_lds double-buffer, 8 blocks/CU, 32 waves/CU.
// Block 0 zeroes the 3 control words (stream order covers k2).
__global__ __launch_bounds__(256) void k1_score(
    const float* __restrict__ logits, const float* __restrict__ reg,
    const float* __restrict__ prop, const int* __restrict__ ph,
    const int* __restrict__ pw, float* __restrict__ scores,
    int* __restrict__ labels, unsigned int* __restrict__ ctl, int N) {
  __shared__ float4 tile[2][TILE4];       // 18432 B
  const int t = threadIdx.x, wv = t >> 6, lane = t & 63;
  if (blockIdx.x == 0 && t < 3) ctl[t * 16] = 0u;   // counter, done1, done2
  const float W = scalar_to_float(pw), H = scalar_to_float(ph);
  const int nchunks = (N + CHUNK - 1) / CHUNK;

  auto stage = [&](int cc, int b) {
    const int rows = min(CHUNK, N - cc * CHUNK);
    const int nf = rows * 91, nf4 = nf >> 2;
    const float4* s4 = (const float4*)(logits + (size_t)cc * CHUNK * 91);
    float4* dst = &tile[b][0];
    #pragma unroll
    for (int k = 0; k < 3; ++k) {
      int b4 = (wv + (k << 2)) << 6;
      if (b4 < nf4) {
        int g = b4 + lane;
        if (g > nf4 - 1) g = nf4 - 1;
        __builtin_amdgcn_global_load_lds(
            (const __attribute__((address_space(1))) void*)(s4 + g),
            (__attribute__((address_space(3))) void*)(dst + b4),
            16, 0, 0);
      }
    }
    for (int i = (nf4 << 2) + t; i < nf; i += 256)
      ((float*)dst)[i] = logits[(size_t)cc * CHUNK * 91 + i];
  };

  int c = blockIdx.x;
  int cur = 0;
  if (c < nchunks) stage(c, 0);
  __syncthreads();
  while (c < nchunks) {
    const int cn = c + gridDim.x;
    if (cn < nchunks) stage(cn, cur ^ 1);
    const int rows = min(CHUNK, N - c * CHUNK);
    const int r = t >> 3, s = t & 7;
    if (r < rows) {
      const float* rowp = (const float*)&tile[cur][0] + r * 91;
      float mv = -3.402823466e38f; int mi = 1 << 20;
      float e0 = 0.f, e1 = 0.f;
      #pragma unroll
      for (int k = 0; k < 12; ++k) {
        int j = s + (k << 3);
        if (j < 91) {
          float v = rowp[j];
          float ex = __expf(v);
          if (k & 1) e1 += ex; else e0 += ex;
          if (v > mv) { mv = v; mi = j; }
        }
      }
      float e = e0 + e1;
      #pragma unroll
      for (int m = 1; m <= 4; m <<= 1) {
        float ov = __shfl_xor(mv, m, 64);
        int   oi = __shfl_xor(mi, m, 64);
        float oe = __shfl_xor(e, m, 64);
        e += oe;
        if (ov > mv || (ov == mv && oi < mi)) { mv = ov; mi = oi; }
      }
      if (s == 0) {
        float top1 = __expf(mv) / e;
        const int row = c * CHUNK + r;
        float4 rg = ((const float4*)reg)[row];
        float4 pp = ((const float4*)prop)[row];
        Box b = decode_clip(rg, pp, W, H);
        bool valid = (top1 > 0.05f) && ((b.x2 - b.x1) >= 0.01f) && ((b.y2 - b.y1) >= 0.01f);
        float sc = valid ? top1 : -1.f;
        scores[row] = sc;
        labels[row] = mi;
      }
    }
    __syncthreads();
    cur ^= 1;
    c = cn;
  }
}

// K2: A) per-block hist -> partials -> done1; B) all blocks cutoff;
// C) compaction -> cand -> done2; D) block 0, WAVE 0 ONLY: barrier-free
// register-resident greedy NMS (exact reference scan semantics).
__global__ __launch_bounds__(1024) void k2_allinone(
    const float* __restrict__ scores, unsigned int* __restrict__ histp,
    unsigned long long* __restrict__ cand, unsigned int* __restrict__ ctl,
    const float* __restrict__ reg, const float* __restrict__ prop,
    const int* __restrict__ labels, const int* __restrict__ ph,
    const int* __restrict__ pw, float* __restrict__ out, int N) {
  __shared__ unsigned int lh[NBINS];
  __shared__ unsigned int wsum[16];
  __shared__ unsigned int wtail[16];
  __shared__ int bstar;
  unsigned int* counter = ctl;
  unsigned int* done1 = ctl + 16;
  unsigned int* done2 = ctl + 32;
  const int t = threadIdx.x;
  const int lane = t & 63, w = t >> 6;
  const int n4 = N >> 2;
  const float4* s4 = (const float4*)scores;
  // ---- A) per-block histogram ----
  lh[t] = 0u;
  if (t == 0) bstar = 0;
  __syncthreads();
  for (int i = blockIdx.x * 1024 + t; i < n4; i += K2GRID * 1024) {
    float4 q = s4[i];
    #pragma unroll
    for (int e = 0; e < 4; ++e) {
      float sc = (e == 0) ? q.x : (e == 1) ? q.y : (e == 2) ? q.z : q.w;
      if (sc > 0.f) {
        int bin = (int)(sc * (float)NBINS);
        if (bin > NBINS - 1) bin = NBINS - 1;
        atomicAdd(&lh[bin], 1u);
      }
    }
  }
  for (int i = (n4 << 2) + blockIdx.x * 1024 + t; i < N; i += K2GRID * 1024) {
    float sc = scores[i];
    if (sc > 0.f) {
      int bin = (int)(sc * (float)NBINS);
      if (bin > NBINS - 1) bin = NBINS - 1;
      atomicAdd(&lh[bin], 1u);
    }
  }
  __syncthreads();
  histp[blockIdx.x * NBINS + t] = lh[t];
  __syncthreads();
  if (t == 0) {
    __threadfence();
    atomicAdd(done1, 1u);
    while (__hip_atomic_load(done1, __ATOMIC_ACQUIRE, __HIP_MEMORY_SCOPE_AGENT)
           < (unsigned int)K2GRID) { }
  }
  __syncthreads();
  // ---- B) cutoff ----
  unsigned int h0 = 0u;
  #pragma unroll 8
  for (int b = 0; b < K2GRID; ++b) h0 += histp[b * NBINS + t];
  unsigned int v = h0;
  #pragma unroll
  for (int m = 1; m < 64; m <<= 1) {
    unsigned int o = __shfl_down(v, m, 64);
    if (lane + m < 64) v += o;
  }
  if (lane == 0) wsum[w] = v;
  __syncthreads();
  if (w == 0) {
    unsigned int u = (lane < 16) ? wsum[lane] : 0u;
    unsigned int inc = u;
    #pragma unroll
    for (int m = 1; m < 16; m <<= 1) {
      unsigned int o = __shfl_down(inc, m, 64);
      if (lane + m < 16) inc += o;
    }
    if (lane < 16) wtail[lane] = inc - u;
  }
  __syncthreads();
  {
    unsigned int St = v + wtail[w];
    unsigned int St1 = St - h0;
    if (St >= TARGETC && St1 < TARGETC) {
      int b = t;
      if (St > CAPW) b = t + 1;     // keep count <= CAPW
      if (b > NBINS - 1) b = NBINS - 1;
      bstar = b;
    }
  }
  __syncthreads();
  const int bs = bstar;
  // ---- C) compaction ----
  auto consider = [&](float sc, int idx) {
    if (sc > 0.f) {
      int bin = (int)(sc * (float)NBINS);
      if (bin > NBINS - 1) bin = NBINS - 1;
      if (bin >= bs) {
        unsigned int pos = atomicAdd(counter, 1u);
        if (pos < CAPC) {
          unsigned long long key =
              ((unsigned long long)__float_as_uint(sc) << 32) |
              (unsigned long long)(0xFFFFFFFFu - (unsigned int)idx);
          __hip_atomic_store(&cand[pos], key, __ATOMIC_RELEASE,
                             __HIP_MEMORY_SCOPE_AGENT);
        }
      }
    }
  };
  for (int i = blockIdx.x * 1024 + t; i < n4; i += K2GRID * 1024) {
    float4 q = s4[i];
    consider(q.x, 4 * i + 0);
    consider(q.y, 4 * i + 1);
    consider(q.z, 4 * i + 2);
    consider(q.w, 4 * i + 3);
  }
  for (int i = (n4 << 2) + blockIdx.x * 1024 + t; i < N; i += K2GRID * 1024)
    consider(scores[i], i);
  __syncthreads();
  if (t == 0) {
    __threadfence();
    atomicAdd(done2, 1u);
  }
  if (blockIdx.x != 0) return;
  // ---- D) block 0: wait, then wave 0 does register NMS (no barriers) ----
  if (t == 0) {
    while (__hip_atomic_load(done2, __ATOMIC_ACQUIRE, __HIP_MEMORY_SCOPE_AGENT)
           < (unsigned int)K2GRID) { }
  }
  __syncthreads();
  unsigned int cnt_u = __hip_atomic_load(counter, __ATOMIC_ACQUIRE,
                                         __HIP_MEMORY_SCOPE_AGENT);
  if (t >= 64) return;            // wave 0 only from here; no __syncthreads below
  int count = (cnt_u < (unsigned int)CAPW) ? (int)cnt_u : CAPW;
  const float W = scalar_to_float(pw), H = scalar_to_float(ph);
  // load candidate slots into registers
  unsigned long long key[NSLOT];
  float bx1[NSLOT], by1[NSLOT], bx2[NSLOT], by2[NSLOT], bsc[NSLOT];
  int blb[NSLOT];
  #pragma unroll
  for (int s = 0; s < NSLOT; ++s) {
    key[s] = 0ULL;
    bx1[s] = 0.f; by1[s] = 0.f; bx2[s] = 0.f; by2[s] = 0.f; bsc[s] = 0.f; blb[s] = -1;
    int j = (s << 6) + t;
    if (j < count) {
      unsigned long long k = __hip_atomic_load(&cand[j], __ATOMIC_RELAXED,
                                               __HIP_MEMORY_SCOPE_AGENT);
      int idx = (int)(0xFFFFFFFFu - (unsigned int)(k & 0xFFFFFFFFULL));
      key[s] = k;
      bsc[s] = __uint_as_float((unsigned int)(k >> 32));
      blb[s] = labels[idx];
      float4 r = ((const float4*)reg)[idx];
      float4 p = ((const float4*)prop)[idx];
      Box b = decode_clip(r, p, W, H);
      bx1[s] = b.x1; by1[s] = b.y1; bx2[s] = b.x2; by2[s] = b.y2;
    }
  }
  int nk = 0;
  for (int it = 0; it < DET; ++it) {
    // local argmax (track values of the local best)
    unsigned long long mk = 0ULL;
    float lx1 = 0.f, ly1 = 0.f, lx2 = 0.f, ly2 = 0.f, lsc = 0.f;
    int llb = -1;
    #pragma unroll
    for (int s = 0; s < NSLOT; ++s) {
      bool g = key[s] > mk;
      mk  = g ? key[s] : mk;
      lx1 = g ? bx1[s] : lx1; ly1 = g ? by1[s] : ly1;
      lx2 = g ? bx2[s] : lx2; ly2 = g ? by2[s] : ly2;
      lsc = g ? bsc[s] : lsc; llb = g ? blb[s] : llb;
    }
    // wave argmax carrying source lane
    unsigned int src = (unsigned int)t;
    #pragma unroll
    for (int m = 1; m < 64; m <<= 1) {
      unsigned long long ok = __shfl_xor(mk, m, 64);
      unsigned int osrc = __shfl_xor(src, m, 64);
      if (ok > mk) { mk = ok; src = osrc; }
    }
    if (mk == 0ULL) break;
    // broadcast the winner's box/label/score from lane src (uniform)
    float wx1 = __shfl(lx1, (int)src, 64);
    float wy1 = __shfl(ly1, (int)src, 64);
    float wx2 = __shfl(lx2, (int)src, 64);
    float wy2 = __shfl(ly2, (int)src, 64);
    float wsc = __shfl(lsc, (int)src, 64);
    int   wlb = __shfl(llb, (int)src, 64);
    if (t == 0) {
      out[nk * 4 + 0] = wx1;
      out[nk * 4 + 1] = wy1;
      out[nk * 4 + 2] = wx2;
      out[nk * 4 + 3] = wy2;
      out[400 + nk] = wsc;
      out[500 + nk] = (float)wlb;
    }
    ++nk;
    // suppression: same-label IoU > 0.5 (division matches reference exactly)
    float warea = (wx2 - wx1) * (wy2 - wy1);
    #pragma unroll
    for (int s = 0; s < NSLOT; ++s) {
      if (key[s] != 0ULL) {
        if (key[s] == mk) {
          key[s] = 0ULL;
        } else if (blb[s] == wlb) {
          float ax = fmaxf(bx1[s], wx1), ay = fmaxf(by1[s], wy1);
          float bx = fminf(bx2[s], wx2), by = fminf(by2[s], wy2);
          float iw = fmaxf(bx - ax, 0.f), ih = fmaxf(by - ay, 0.f);
          float inter = iw * ih;
          float a2 = (bx2[s] - bx1[s]) * (by2[s] - by1[s]);
          float iou = inter / (warea + a2 - inter);
          if (iou > 0.5f) key[s] = 0ULL;
        }
      }
    }
  }
  // pad remaining detections
  if (t == 0) {
    for (int it = nk; it < DET; ++it) {
      out[it * 4 + 0] = 0.f; out[it * 4 + 1] = 0.f;
      out[it * 4 + 2] = 0.f; out[it * 4 + 3] = 0.f;
      out[400 + it] = 0.f;
      out[500 + it] = -1.f;
    }
  }
}

extern "C" void kernel_launch(void* const* d_in, const int* in_sizes, int n_in,
                              void* d_out, int out_size, void* d_ws, size_t ws_size,
                              hipStream_t stream) {
  const float* logits = (const float*)d_in[0];
  const float* reg    = (const float*)d_in[1];
  const float* prop   = (const float*)d_in[2];
  const int*   ph     = (const int*)d_in[3];
  const int*   pw     = (const int*)d_in[4];
  float* out = (float*)d_out;

  const int N = in_sizes[1] / 4;

  char* ws = (char*)d_ws;
  float* scores = (float*)ws;                                  // N f32
  int* labels   = (int*)(ws + (size_t)N * 4);                  // N i32
  size_t off = (size_t)N * 8;
  off = (off + 255) & ~(size_t)255;
  unsigned int* ctl = (unsigned int*)(ws + off);               // 64 u32 control
  unsigned int* histp = ctl + 64;                              // K2GRID*NBINS u32
  unsigned long long* cand =
      (unsigned long long*)(ws + off + (64 + K2GRID * NBINS) * 4 + 64);

  k1_score<<<2048, 256, 0, stream>>>(logits, reg, prop, ph, pw, scores, labels, ctl, N);
  k2_allinone<<<K2GRID, 1024, 0, stream>>>(scores, histp, cand, ctl,
                                           reg, prop, labels, ph, pw, out, N);
}

// Round 17
// 58.090 us; speedup vs baseline: 2.1862x; 2.1862x over previous
//
#include <hip/hip_runtime.h>

#define NBINS   1024
#define CAPC    4096
#define TARGETC 192
#define CAPW    256    // hard cap on compacted candidates (cutoff guarantees <=)
#define DET     100
#define XCLIP   4.135166556742356f
#define CHUNK   24
#define TILE4   576    // 546 used float4 slots + clamp pad
#define K2GRID  64     // 1 block/CU -> guaranteed co-resident

__device__ inline float scalar_to_float(const int* p) {
  int v = *p;
  return (v >= 0 && v < (1 << 20)) ? (float)v : __int_as_float(v);
}

struct Box { float x1, y1, x2, y2; };

__device__ inline Box decode_clip(float4 r, float4 p, float W, float H) {
  float w = p.z - p.x, h = p.w - p.y;
  float cx = p.x + 0.5f * w, cy = p.y + 0.5f * h;
  float dx = r.x / 10.f, dy = r.y / 10.f;
  float dw = fminf(r.z / 5.f, XCLIP), dh = fminf(r.w / 5.f, XCLIP);
  float pcx = dx * w + cx, pcy = dy * h + cy;
  float pw = __expf(dw) * w, ph = __expf(dh) * h;
  Box b;
  b.x1 = fminf(fmaxf(pcx - 0.5f * pw, 0.f), W);
  b.y1 = fminf(fmaxf(pcy - 0.5f * ph, 0.f), H);
  b.x2 = fminf(fmaxf(pcx + 0.5f * pw, 0.f), W);
  b.y2 = fminf(fmaxf(pcy + 0.5f * ph, 0.f), H);
  return b;
}

// K1 (unchanged): global_load_lds double-buffer, 8 blocks/CU, 32 waves/CU.
// Block 0 zeroes the 3 control words (stream order covers k2).
__global__ __launch_bounds__(256) void k1_score(
    const float* __restrict__ logits, const float* __restrict__ reg,
    const float* __restrict__ prop, const int* __restrict__ ph,
    const int* __restrict__ pw, float* __restrict__ scores,
    int* __restrict__ labels, unsigned int* __restrict__ ctl, int N) {
  __shared__ float4 tile[2][TILE4];       // 18432 B
  const int t = threadIdx.x, wv = t >> 6, lane = t & 63;
  if (blockIdx.x == 0 && t < 3) ctl[t * 16] = 0u;   // counter, done1, done2
  const float W = scalar_to_float(pw), H = scalar_to_float(ph);
  const int nchunks = (N + CHUNK - 1) / CHUNK;

  auto stage = [&](int cc, int b) {
    const int rows = min(CHUNK, N - cc * CHUNK);
    const int nf = rows * 91, nf4 = nf >> 2;
    const float4* s4 = (const float4*)(logits + (size_t)cc * CHUNK * 91);
    float4* dst = &tile[b][0];
    #pragma unroll
    for (int k = 0; k < 3; ++k) {
      int b4 = (wv + (k << 2)) << 6;
      if (b4 < nf4) {
        int g = b4 + lane;
        if (g > nf4 - 1) g = nf4 - 1;
        __builtin_amdgcn_global_load_lds(
            (const __attribute__((address_space(1))) void*)(s4 + g),
            (__attribute__((address_space(3))) void*)(dst + b4),
            16, 0, 0);
      }
    }
    for (int i = (nf4 << 2) + t; i < nf; i += 256)
      ((float*)dst)[i] = logits[(size_t)cc * CHUNK * 91 + i];
  };

  int c = blockIdx.x;
  int cur = 0;
  if (c < nchunks) stage(c, 0);
  __syncthreads();
  while (c < nchunks) {
    const int cn = c + gridDim.x;
    if (cn < nchunks) stage(cn, cur ^ 1);
    const int rows = min(CHUNK, N - c * CHUNK);
    const int r = t >> 3, s = t & 7;
    if (r < rows) {
      const float* rowp = (const float*)&tile[cur][0] + r * 91;
      float mv = -3.402823466e38f; int mi = 1 << 20;
      float e0 = 0.f, e1 = 0.f;
      #pragma unroll
      for (int k = 0; k < 12; ++k) {
        int j = s + (k << 3);
        if (j < 91) {
          float v = rowp[j];
          float ex = __expf(v);
          if (k & 1) e1 += ex; else e0 += ex;
          if (v > mv) { mv = v; mi = j; }
        }
      }
      float e = e0 + e1;
      #pragma unroll
      for (int m = 1; m <= 4; m <<= 1) {
        float ov = __shfl_xor(mv, m, 64);
        int   oi = __shfl_xor(mi, m, 64);
        float oe = __shfl_xor(e, m, 64);
        e += oe;
        if (ov > mv || (ov == mv && oi < mi)) { mv = ov; mi = oi; }
      }
      if (s == 0) {
        float top1 = __expf(mv) / e;
        const int row = c * CHUNK + r;
        float4 rg = ((const float4*)reg)[row];
        float4 pp = ((const float4*)prop)[row];
        Box b = decode_clip(rg, pp, W, H);
        bool valid = (top1 > 0.05f) && ((b.x2 - b.x1) >= 0.01f) && ((b.y2 - b.y1) >= 0.01f);
        float sc = valid ? top1 : -1.f;
        scores[row] = sc;
        labels[row] = mi;
      }
    }
    __syncthreads();
    cur ^= 1;
    c = cn;
  }
}

// K2: A) per-block hist -> partials -> done1; B) cutoff; C) compaction -> done2;
// D) block 0: rank-order (no sort), parallel pairwise suppression matrix,
//    single-thread register-bitmask greedy resolve, parallel output.
__global__ __launch_bounds__(1024) void k2_allinone(
    const float* __restrict__ scores, unsigned int* __restrict__ histp,
    unsigned long long* __restrict__ cand, unsigned int* __restrict__ ctl,
    const float* __restrict__ reg, const float* __restrict__ prop,
    const int* __restrict__ labels, const int* __restrict__ ph,
    const int* __restrict__ pw, float* __restrict__ out, int N) {
  __shared__ unsigned int lh[NBINS];
  __shared__ unsigned int wsum[16];
  __shared__ unsigned int wtail[16];
  __shared__ int bstar;
  __shared__ unsigned long long keys[CAPW];
  __shared__ float rx1[CAPW], ry1[CAPW], rx2[CAPW], ry2[CAPW], rsc[CAPW];
  __shared__ int rlab[CAPW];
  __shared__ unsigned int sup[CAPW * 8];   // 256x256-bit suppression matrix
  __shared__ unsigned int rowAny[8];       // per-candidate "row nonzero" bits
  __shared__ int keepL[DET];
  __shared__ int nkS;
  unsigned int* counter = ctl;
  unsigned int* done1 = ctl + 16;
  unsigned int* done2 = ctl + 32;
  const int t = threadIdx.x;
  const int lane = t & 63, w = t >> 6;
  const int n4 = N >> 2;
  const float4* s4 = (const float4*)scores;
  // ---- A) per-block histogram ----
  lh[t] = 0u;
  if (t == 0) bstar = 0;
  __syncthreads();
  for (int i = blockIdx.x * 1024 + t; i < n4; i += K2GRID * 1024) {
    float4 q = s4[i];
    #pragma unroll
    for (int e = 0; e < 4; ++e) {
      float sc = (e == 0) ? q.x : (e == 1) ? q.y : (e == 2) ? q.z : q.w;
      if (sc > 0.f) {
        int bin = (int)(sc * (float)NBINS);
        if (bin > NBINS - 1) bin = NBINS - 1;
        atomicAdd(&lh[bin], 1u);
      }
    }
  }
  for (int i = (n4 << 2) + blockIdx.x * 1024 + t; i < N; i += K2GRID * 1024) {
    float sc = scores[i];
    if (sc > 0.f) {
      int bin = (int)(sc * (float)NBINS);
      if (bin > NBINS - 1) bin = NBINS - 1;
      atomicAdd(&lh[bin], 1u);
    }
  }
  __syncthreads();
  histp[blockIdx.x * NBINS + t] = lh[t];
  __syncthreads();
  if (t == 0) {
    __threadfence();
    atomicAdd(done1, 1u);
    while (__hip_atomic_load(done1, __ATOMIC_ACQUIRE, __HIP_MEMORY_SCOPE_AGENT)
           < (unsigned int)K2GRID) { }
  }
  __syncthreads();
  // ---- B) cutoff ----
  unsigned int h0 = 0u;
  #pragma unroll 8
  for (int b = 0; b < K2GRID; ++b) h0 += histp[b * NBINS + t];
  unsigned int v = h0;
  #pragma unroll
  for (int m = 1; m < 64; m <<= 1) {
    unsigned int o = __shfl_down(v, m, 64);
    if (lane + m < 64) v += o;
  }
  if (lane == 0) wsum[w] = v;
  __syncthreads();
  if (w == 0) {
    unsigned int u = (lane < 16) ? wsum[lane] : 0u;
    unsigned int inc = u;
    #pragma unroll
    for (int m = 1; m < 16; m <<= 1) {
      unsigned int o = __shfl_down(inc, m, 64);
      if (lane + m < 16) inc += o;
    }
    if (lane < 16) wtail[lane] = inc - u;
  }
  __syncthreads();
  {
    unsigned int St = v + wtail[w];
    unsigned int St1 = St - h0;
    if (St >= TARGETC && St1 < TARGETC) {
      int b = t;
      if (St > CAPW) b = t + 1;     // keep count <= CAPW
      if (b > NBINS - 1) b = NBINS - 1;
      bstar = b;
    }
  }
  __syncthreads();
  const int bs = bstar;
  // ---- C) compaction ----
  auto consider = [&](float sc, int idx) {
    if (sc > 0.f) {
      int bin = (int)(sc * (float)NBINS);
      if (bin > NBINS - 1) bin = NBINS - 1;
      if (bin >= bs) {
        unsigned int pos = atomicAdd(counter, 1u);
        if (pos < CAPC) {
          unsigned long long key =
              ((unsigned long long)__float_as_uint(sc) << 32) |
              (unsigned long long)(0xFFFFFFFFu - (unsigned int)idx);
          __hip_atomic_store(&cand[pos], key, __ATOMIC_RELEASE,
                             __HIP_MEMORY_SCOPE_AGENT);
        }
      }
    }
  };
  for (int i = blockIdx.x * 1024 + t; i < n4; i += K2GRID * 1024) {
    float4 q = s4[i];
    consider(q.x, 4 * i + 0);
    consider(q.y, 4 * i + 1);
    consider(q.z, 4 * i + 2);
    consider(q.w, 4 * i + 3);
  }
  for (int i = (n4 << 2) + blockIdx.x * 1024 + t; i < N; i += K2GRID * 1024)
    consider(scores[i], i);
  __syncthreads();
  if (t == 0) {
    __threadfence();
    atomicAdd(done2, 1u);
  }
  if (blockIdx.x != 0) return;
  // ---- D) block 0 only ----
  if (t == 0) {
    while (__hip_atomic_load(done2, __ATOMIC_ACQUIRE, __HIP_MEMORY_SCOPE_AGENT)
           < (unsigned int)K2GRID) { }
  }
  __syncthreads();
  unsigned int cnt_u = __hip_atomic_load(counter, __ATOMIC_ACQUIRE,
                                         __HIP_MEMORY_SCOPE_AGENT);
  const int count = (cnt_u < (unsigned int)CAPW) ? (int)cnt_u : CAPW;
  const float W = scalar_to_float(pw), H = scalar_to_float(ph);
  // D1: load keys to LDS
  unsigned long long myKey = 0ULL;
  if (t < CAPW) {
    if (t < count)
      myKey = __hip_atomic_load(&cand[t], __ATOMIC_RELAXED,
                                __HIP_MEMORY_SCOPE_AGENT);
    keys[t] = myKey;
  }
  __syncthreads();
  // D2: rank = #{j: key_j > myKey}; decode box into rank-ordered arrays
  if (t < count) {
    int r = 0;
    for (int j = 0; j < count; ++j) r += (keys[j] > myKey) ? 1 : 0;
    int idx = (int)(0xFFFFFFFFu - (unsigned int)(myKey & 0xFFFFFFFFULL));
    float4 rr = ((const float4*)reg)[idx];
    float4 pp = ((const float4*)prop)[idx];
    Box b = decode_clip(rr, pp, W, H);
    rx1[r] = b.x1; ry1[r] = b.y1; rx2[r] = b.x2; ry2[r] = b.y2;
    rsc[r] = __uint_as_float((unsigned int)(myKey >> 32));
    rlab[r] = labels[idx];
  }
  // D3: zero suppression matrix + flags
  sup[t] = 0u; sup[t + 1024] = 0u;
  if (t < 8) rowAny[t] = 0u;
  if (t == 0) nkS = 0;
  __syncthreads();
  // D4: pairwise suppression (a suppresses later b), label filter first
  for (int p = t; p < (count << 8); p += 1024) {
    int a = p >> 8, b = p & 255;
    if (a < b && b < count && rlab[a] == rlab[b]) {
      float ax = fmaxf(rx1[a], rx1[b]), ay = fmaxf(ry1[a], ry1[b]);
      float bx = fminf(rx2[a], rx2[b]), by = fminf(ry2[a], ry2[b]);
      float iw = fmaxf(bx - ax, 0.f), ih = fmaxf(by - ay, 0.f);
      float inter = iw * ih;
      float a1 = (rx2[a] - rx1[a]) * (ry2[a] - ry1[a]);
      float a2 = (rx2[b] - rx1[b]) * (ry2[b] - ry1[b]);
      if (inter / (a1 + a2 - inter) > 0.5f) {
        atomicOr(&sup[a * 8 + (b >> 5)], 1u << (b & 31));
        atomicOr(&rowAny[a >> 5], 1u << (a & 31));
      }
    }
  }
  __syncthreads();
  // D5: serial greedy resolve, thread 0, all mask words in named registers
  if (t == 0) {
    unsigned int m0 = 0, m1 = 0, m2 = 0, m3 = 0, m4 = 0, m5 = 0, m6 = 0, m7 = 0;
    int nk = 0;
#define RESOLVE_WORD(WI, MREG)                                          \
    if (nk < DET && (WI) * 32 < count) {                                \
      unsigned int anyw = rowAny[WI];                                   \
      int lim = count - (WI) * 32; if (lim > 32) lim = 32;              \
      for (int b = 0; b < lim; ++b) {                                   \
        if (nk >= DET) break;                                           \
        if (!((MREG >> b) & 1u)) {                                      \
          int p = (WI) * 32 + b;                                        \
          keepL[nk++] = p;                                              \
          if ((anyw >> b) & 1u) {                                       \
            const unsigned int* row = &sup[p * 8];                      \
            m0 |= row[0]; m1 |= row[1]; m2 |= row[2]; m3 |= row[3];     \
            m4 |= row[4]; m5 |= row[5]; m6 |= row[6]; m7 |= row[7];     \
          }                                                             \
        }                                                               \
      }                                                                 \
    }
    RESOLVE_WORD(0, m0)
    RESOLVE_WORD(1, m1)
    RESOLVE_WORD(2, m2)
    RESOLVE_WORD(3, m3)
    RESOLVE_WORD(4, m4)
    RESOLVE_WORD(5, m5)
    RESOLVE_WORD(6, m6)
    RESOLVE_WORD(7, m7)
#undef RESOLVE_WORD
    nkS = nk;
  }
  __syncthreads();
  // D6: output
  if (t < DET) {
    int nk = nkS;
    bool vld = t < nk;
    int p = vld ? keepL[t] : 0;
    out[t * 4 + 0] = vld ? rx1[p] : 0.f;
    out[t * 4 + 1] = vld ? ry1[p] : 0.f;
    out[t * 4 + 2] = vld ? rx2[p] : 0.f;
    out[t * 4 + 3] = vld ? ry2[p] : 0.f;
    out[400 + t] = vld ? rsc[p] : 0.f;
    out[500 + t] = vld ? (float)rlab[p] : -1.f;
  }
}

extern "C" void kernel_launch(void* const* d_in, const int* in_sizes, int n_in,
                              void* d_out, int out_size, void* d_ws, size_t ws_size,
                              hipStream_t stream) {
  const float* logits = (const float*)d_in[0];
  const float* reg    = (const float*)d_in[1];
  const float* prop   = (const float*)d_in[2];
  const int*   ph     = (const int*)d_in[3];
  const int*   pw     = (const int*)d_in[4];
  float* out = (float*)d_out;

  const int N = in_sizes[1] / 4;

  char* ws = (char*)d_ws;
  float* scores = (float*)ws;                                  // N f32
  int* labels   = (int*)(ws + (size_t)N * 4);                  // N i32
  size_t off = (size_t)N * 8;
  off = (off + 255) & ~(size_t)255;
  unsigned int* ctl = (unsigned int*)(ws + off);               // 64 u32 control
  unsigned int* histp = ctl + 64;                              // K2GRID*NBINS u32
  unsigned long long* cand =
      (unsigned long long*)(ws + off + (64 + K2GRID * NBINS) * 4 + 64);

  k1_score<<<2048, 256, 0, stream>>>(logits, reg, prop, ph, pw, scores, labels, ctl, N);
  k2_allinone<<<K2GRID, 1024, 0, stream>>>(scores, histp, cand, ctl,
                                           reg, prop, labels, ph, pw, out, N);
}